// Round 8
// baseline (356.881 us; speedup 1.0000x reference)
//
#include <hip/hip_runtime.h>
#include <hip/hip_bf16.h>

// ---------------------------------------------------------------------------
// UpSampler: 3x sparse 3^3 conv (MFMA bf16) -> fused tconv+dec
// R8: compose the measured-best variant of each kernel:
//   convA (CH=1): R6 LDS-B 32-row/wave barrier-per-ko (stable, ~62-66 us).
//   convB (CH=2): R3 K-split register-B pipeline (measured 59 us): 64-row
//     tile, wave0 ko 0-12 (+bias) / wave1 ko 13-26, B+A register double
//     buffers prefetched 1 ko ahead, idx 2 ahead, NO barrier in K-loop.
//     (R7 regressed because B was loaded in the consuming step — latency on
//     the serial chain. R3 proved the 1-ahead B prefetch is the difference.)
//   Separate named kernels (not one body with branches): R4 showed merging
//   paths into one function spills both; R3 showed separate instantiations
//   keep the good one clean.
//   tconv_dec_k / prep_k: R6 verbatim (69 us / ~14 us; tconv has a ~±20%
//   context-noise band across rounds — don't read small deltas).
// ---------------------------------------------------------------------------
#define NC 100000      // N_COARSE
#define MF 400000      // M_FINE
#define K3 27

typedef __bf16 bf16_t;
typedef bf16_t bf16x8 __attribute__((ext_vector_type(8)));
typedef float  f32x4  __attribute__((ext_vector_type(4)));

// Repacked-weight offsets (elements) inside g_w
#define O_E1 0                       // 27*1*4*512 = 55296
#define O_E2 55296                   // 27*2*4*512 = 110592
#define O_E3 165888                  // 110592
#define O_T  276480                  // 8*2*4*512 = 32768
#define O_D1 309248                  // 2*4*512 = 4096
#define O_D2 313344                  // 2*2*512 = 2048
#define W_TOTAL 315392

__device__ __align__(16) bf16_t g_w[W_TOTAL];
__device__ __align__(16) bf16_t g_x0[(size_t)NC * 32];  // bf16 feats
__device__ __align__(16) bf16_t g_x1[(size_t)NC * 64];
__device__ __align__(16) bf16_t g_x2[(size_t)NC * 64];
__device__ int g_nbrT[(size_t)K3 * NC];                 // transposed rulebook

static __device__ __forceinline__ bf16x8 zero8() {
    bf16x8 v;
#pragma unroll
    for (int i = 0; i < 8; ++i) v[i] = (bf16_t)0.0f;
    return v;
}

// ---------------------------------------------------------------------------
// Fused prep: (a) repack fp32 weights -> bf16 MFMA B-frags; (b) feats fp32 ->
// bf16; (c) transpose nbr [NC,27] -> g_nbrT [27,NC].
// Blocks [0,154): repack. [154,1717): feats. [1717,2108): nbr transpose.
// ---------------------------------------------------------------------------
__global__ __launch_bounds__(256) void prep_k(
    const float* __restrict__ W_e1, const float* __restrict__ W_e2,
    const float* __restrict__ W_e3, const float* __restrict__ W_t,
    const float* __restrict__ W_d1, const float* __restrict__ W_d2,
    const float* __restrict__ feats, const int* __restrict__ nbr)
{
    int b = blockIdx.x;
    if (b < 154) {
        int tid = b * 256 + threadIdx.x;
        int lane = tid & 63;
        int f = tid >> 6;            // 0..615
        const float* src; int doff, nt, nc, fb;
        if      (f < 108) { src = W_e1; doff = O_E1; nt = 4; nc = 1; fb = 0;   }
        else if (f < 324) { src = W_e2; doff = O_E2; nt = 4; nc = 2; fb = 108; }
        else if (f < 540) { src = W_e3; doff = O_E3; nt = 4; nc = 2; fb = 324; }
        else if (f < 604) { src = W_t;  doff = O_T;  nt = 4; nc = 2; fb = 540; }
        else if (f < 612) { src = W_d1; doff = O_D1; nt = 4; nc = 2; fb = 604; }
        else              { src = W_d2; doff = O_D2; nt = 2; nc = 2; fb = 612; }
        int lf = f - fb;
        int t  = lf % nt;
        int c  = (lf / nt) % nc;
        int ko = lf / (nt * nc);
        int Cin = nc * 32, Cout = nt * 16;
        int n  = t * 16 + (lane & 15);
        int kb = c * 32 + (lane >> 4) * 8;
        bf16x8 tmp;
#pragma unroll
        for (int j = 0; j < 8; ++j)
            tmp[j] = (bf16_t)src[((size_t)ko * Cin + (kb + j)) * Cout + n];
        *(bf16x8*)(g_w + doff + (size_t)lf * 512 + lane * 8) = tmp;
    } else if (b < 1717) {
        int i = (b - 154) * 256 + threadIdx.x;   // chunk of 8 floats
        if (i < NC * 32 / 8) {
            const f32x4* p = (const f32x4*)(feats + (size_t)i * 8);
            f32x4 lo = p[0], hi = p[1];
            bf16x8 v;
#pragma unroll
            for (int j = 0; j < 4; ++j) { v[j] = (bf16_t)lo[j]; v[j + 4] = (bf16_t)hi[j]; }
            *(bf16x8*)(g_x0 + (size_t)i * 8) = v;
        }
    } else {
        int r = (b - 1717) * 256 + threadIdx.x;
        if (r < NC) {
#pragma unroll
            for (int k = 0; k < K3; ++k)
                g_nbrT[(size_t)k * NC + r] = nbr[(size_t)r * K3 + k];
        }
    }
}

// ---------------------------------------------------------------------------
// convA (CH=1, feats 32ch -> 64ch): R6 structure. 2 waves/block, 32 rows/
// wave. B[ko] double-buffered in LDS (staged cooperatively), one barrier per
// ko. idx 2-ahead, A-gathers 1-ahead (literal parity). ~110 VGPR.
// Grid must be a multiple of 8 (XCD swizzle).
// ---------------------------------------------------------------------------
#define TS 72   // transpose row stride (bf16): 144B, 16B-aligned

#define ASTEP(KO, P) do {                                                      \
    if ((KO) + 1 < K3) {                                                       \
        const bf16x8* s_ = (const bf16x8*)(wsrc + (size_t)((KO) + 1) * 2048);  \
        bf16x8* d_ = (bf16x8*)bB[(P) ^ 1];                                     \
        _Pragma("unroll")                                                      \
        for (int i_ = 0; i_ < 2; ++i_)                                         \
            d_[i_ * 128 + tid] = s_[i_ * 128 + tid];                           \
        _Pragma("unroll")                                                      \
        for (int mt_ = 0; mt_ < 2; ++mt_) {                                    \
            int ii_ = idxbuf[(P) ^ 1][mt_];                                    \
            bool va_ = (unsigned)ii_ < (unsigned)NC;                           \
            int ss_ = va_ ? ii_ : 0;                                           \
            bf16x8 a_ = *(const bf16x8*)(xb + (size_t)ss_ * 32 + q * 8);       \
            if (!va_) a_ = zero8();                                            \
            abuf[(P) ^ 1][mt_] = a_;                                           \
        }                                                                      \
    }                                                                          \
    if ((KO) + 2 < K3) {                                                       \
        _Pragma("unroll")                                                      \
        for (int mt_ = 0; mt_ < 2; ++mt_) {                                    \
            int r_ = base + mt_ * 16 + cl;                                     \
            idxbuf[P][mt_] = (r_ < NC) ? g_nbrT[(size_t)((KO) + 2) * NC + r_] : NC; \
        }                                                                      \
    }                                                                          \
    {                                                                          \
        bf16x8 bfr_[4];                                                        \
        _Pragma("unroll")                                                      \
        for (int t_ = 0; t_ < 4; ++t_)                                         \
            bfr_[t_] = *(const bf16x8*)&bB[P][t_ * 512 + lane * 8];            \
        _Pragma("unroll")                                                      \
        for (int mt_ = 0; mt_ < 2; ++mt_)                                      \
            _Pragma("unroll")                                                  \
            for (int t_ = 0; t_ < 4; ++t_)                                     \
                acc[mt_][t_] = __builtin_amdgcn_mfma_f32_16x16x32_bf16(        \
                    abuf[P][mt_], bfr_[t_], acc[mt_][t_], 0, 0, 0);            \
    }                                                                          \
    __syncthreads();                                                           \
} while (0)

__global__ __launch_bounds__(128, 2) void convA_k(
    const float* __restrict__ bias)   // [64] fp32; src g_x0, dst g_x1
{
    const bf16_t* xb = g_x0;
    bf16_t* y = g_x1;
    const bf16_t* wsrc = g_w + O_E1;

    __shared__ __align__(16) bf16_t bB[2][2048];   // 8 KB: 4 frags/ko
    int tid = threadIdx.x;
    int wv = tid >> 6, lane = tid & 63;
    int cl = lane & 15, q = lane >> 4;

    int per = gridDim.x >> 3;
    int blk = (blockIdx.x & 7) * per + (blockIdx.x >> 3);
    int base = blk * 64 + wv * 32;   // 32 rows per wave

    // stage B[0] (both waves cooperate)
    {
        const bf16x8* s = (const bf16x8*)wsrc;
        bf16x8* d = (bf16x8*)bB[0];
#pragma unroll
        for (int i = 0; i < 2; ++i) d[i * 128 + tid] = s[i * 128 + tid];
    }

    int idxbuf[2][2];
    bf16x8 abuf[2][2];
#pragma unroll
    for (int mt = 0; mt < 2; ++mt) {
        int r = base + mt * 16 + cl;
        idxbuf[0][mt] = (r < NC) ? g_nbrT[(size_t)0 * NC + r] : NC;
    }
#pragma unroll
    for (int mt = 0; mt < 2; ++mt) {
        int ii = idxbuf[0][mt];
        bool va = (unsigned)ii < (unsigned)NC;
        int ss = va ? ii : 0;
        bf16x8 a = *(const bf16x8*)(xb + (size_t)ss * 32 + q * 8);
        if (!va) a = zero8();
        abuf[0][mt] = a;
    }
#pragma unroll
    for (int mt = 0; mt < 2; ++mt) {
        int r = base + mt * 16 + cl;
        idxbuf[1][mt] = (r < NC) ? g_nbrT[(size_t)1 * NC + r] : NC;
    }

    f32x4 acc[2][4];
#pragma unroll
    for (int t = 0; t < 4; ++t) {
        float b = bias[t * 16 + cl];
#pragma unroll
        for (int mt = 0; mt < 2; ++mt) acc[mt][t] = (f32x4){b, b, b, b};
    }
    __syncthreads();   // B[0] staged

    for (int ko = 0; ko < K3 - 1; ko += 2) {
        ASTEP(ko, 0);
        ASTEP(ko + 1, 1);
    }
    ASTEP(K3 - 1, 0);

    // relu -> per-wave LDS transpose (reuse bB; dead after final barrier)
    bf16_t* tb = ((bf16_t*)bB) + wv * 2304;   // 32 rows * 72 per wave
#pragma unroll
    for (int mt2 = 0; mt2 < 2; ++mt2)
#pragma unroll
        for (int t = 0; t < 4; ++t)
#pragma unroll
            for (int r = 0; r < 4; ++r) {
                float v = acc[mt2][t][r];
                v = v > 0.0f ? v : 0.0f;
                tb[(mt2 * 16 + q * 4 + r) * TS + t * 16 + cl] = (bf16_t)v;
            }
#pragma unroll
    for (int i = 0; i < 4; ++i) {
        int rl = i * 8 + (lane >> 3);      // 0..31
        int c8 = (lane & 7) * 8;
        bf16x8 v8 = *(const bf16x8*)&tb[rl * TS + c8];
        int orow = base + rl;
        if (orow < NC)
            *(bf16x8*)(y + (size_t)orow * 64 + c8) = v8;
    }
}

// ---------------------------------------------------------------------------
// convB (CH=2, 64ch -> 64ch): R3's measured-59us K-split register pipeline.
// 2 waves/block, ONE 64-row tile. Wave0 ko 0..12 (+bias), wave1 ko 13..26.
// B AND A prefetched 1 ko ahead into register double buffers, idx 2 ahead
// (literal parity). NO LDS / NO barriers in K-loop. launch_bounds(128,2)
// caps VGPR at 256. Cross-wave reduce via XOR-swizzled LDS; each wave
// stores 32 output rows. Grid must be a multiple of 8.
// ---------------------------------------------------------------------------
#define BSTEP(KO, P) do {                                                      \
    if ((KO) + 1 < kend) {                                                     \
        const bf16_t* wb_ = wsrc + (size_t)((KO) + 1) * 4096 + lane * 8;       \
        _Pragma("unroll")                                                      \
        for (int c_ = 0; c_ < 2; ++c_)                                         \
            _Pragma("unroll")                                                  \
            for (int t_ = 0; t_ < 4; ++t_)                                     \
                bbuf[(P) ^ 1][c_][t_] =                                        \
                    *(const bf16x8*)(wb_ + (size_t)(c_ * 4 + t_) * 512);       \
        _Pragma("unroll")                                                      \
        for (int c_ = 0; c_ < 2; ++c_)                                         \
            _Pragma("unroll")                                                  \
            for (int mt_ = 0; mt_ < 4; ++mt_) {                                \
                int ii_ = idxbuf[(P) ^ 1][mt_];                                \
                bool va_ = (unsigned)ii_ < (unsigned)NC;                       \
                int ss_ = va_ ? ii_ : 0;                                       \
                bf16x8 a_ = *(const bf16x8*)(xb + (size_t)ss_ * 64 + c_ * 32 + q * 8); \
                if (!va_) a_ = zero8();                                        \
                abuf[(P) ^ 1][c_][mt_] = a_;                                   \
            }                                                                  \
    }                                                                          \
    if ((KO) + 2 < kend) {                                                     \
        _Pragma("unroll")                                                      \
        for (int mt_ = 0; mt_ < 4; ++mt_) {                                    \
            int r_ = base + mt_ * 16 + cl;                                     \
            idxbuf[P][mt_] = (r_ < NC) ? g_nbrT[(size_t)((KO) + 2) * NC + r_] : NC; \
        }                                                                      \
    }                                                                          \
    _Pragma("unroll")                                                          \
    for (int c_ = 0; c_ < 2; ++c_)                                             \
        _Pragma("unroll")                                                      \
        for (int mt_ = 0; mt_ < 4; ++mt_)                                      \
            _Pragma("unroll")                                                  \
            for (int t_ = 0; t_ < 4; ++t_)                                     \
                acc[mt_][t_] = __builtin_amdgcn_mfma_f32_16x16x32_bf16(        \
                    abuf[P][c_][mt_], bbuf[P][c_][t_], acc[mt_][t_], 0, 0, 0); \
} while (0)

__global__ __launch_bounds__(128, 2) void convB_k(
    int w_off,
    const float* __restrict__ bias,  // [64] fp32
    int src_sel)                     // 1 = g_x1 -> g_x2 ; 2 = g_x2 -> g_x1
{
    const bf16_t* xb = (src_sel == 1) ? g_x1 : g_x2;
    bf16_t* y = (src_sel == 1) ? g_x2 : g_x1;
    const bf16_t* wsrc = g_w + w_off;

    // 16 KB: cross-wave K-reduce buffer; aliased as transpose tiles afterwards
    __shared__ __align__(16) float red[2][2048];

    int tid = threadIdx.x;
    int wv = tid >> 6, lane = tid & 63;
    int cl = lane & 15, q = lane >> 4;

    int per = gridDim.x >> 3;
    int blk = (blockIdx.x & 7) * per + (blockIdx.x >> 3);
    int base = blk * 64;

    int kbeg = wv ? 13 : 0;
    int kend = wv ? K3 : 13;

    int idxbuf[2][4];
    bf16x8 abuf[2][2][4];
    bf16x8 bbuf[2][2][4];

    // pipeline prologue: idx[kbeg] -> gather A, load B; idx[kbeg+1]
#pragma unroll
    for (int mt = 0; mt < 4; ++mt) {
        int r = base + mt * 16 + cl;
        idxbuf[0][mt] = (r < NC) ? g_nbrT[(size_t)kbeg * NC + r] : NC;
    }
    {
        const bf16_t* wb = wsrc + (size_t)kbeg * 4096 + lane * 8;
#pragma unroll
        for (int c = 0; c < 2; ++c)
#pragma unroll
            for (int t = 0; t < 4; ++t)
                bbuf[0][c][t] = *(const bf16x8*)(wb + (size_t)(c * 4 + t) * 512);
    }
#pragma unroll
    for (int c = 0; c < 2; ++c)
#pragma unroll
        for (int mt = 0; mt < 4; ++mt) {
            int ii = idxbuf[0][mt];
            bool va = (unsigned)ii < (unsigned)NC;
            int ss = va ? ii : 0;
            bf16x8 a = *(const bf16x8*)(xb + (size_t)ss * 64 + c * 32 + q * 8);
            if (!va) a = zero8();
            abuf[0][c][mt] = a;
        }
#pragma unroll
    for (int mt = 0; mt < 4; ++mt) {
        int r = base + mt * 16 + cl;
        idxbuf[1][mt] = (r < NC) ? g_nbrT[(size_t)(kbeg + 1) * NC + r] : NC;
    }

    f32x4 acc[4][4];
#pragma unroll
    for (int t = 0; t < 4; ++t) {
        float b = wv ? 0.0f : bias[t * 16 + cl];
#pragma unroll
        for (int mt = 0; mt < 4; ++mt) acc[mt][t] = (f32x4){b, b, b, b};
    }

    int ko = kbeg;
    for (; ko + 1 < kend; ko += 2) {
        BSTEP(ko, 0);
        BSTEP(ko + 1, 1);
    }
    if (ko < kend) BSTEP(ko, 0);   // wave0 tail: ko=12, parity 0

    // ---- cross-wave K-reduce (XOR-swizzled f32x4 slots: conflict-free) ----
    // wave wv exports the mt-half it does NOT output: wv0 -> mt{2,3}, wv1 -> mt{0,1}
    {
        float* rb = red[wv];
#pragma unroll
        for (int m2 = 0; m2 < 2; ++m2)
#pragma unroll
            for (int t = 0; t < 4; ++t) {
                int mt = (wv ? 0 : 2) + m2;
                int k = m2 * 4 + t;
                *(f32x4*)&rb[lane * 32 + ((k ^ (lane & 7)) << 2)] = acc[mt][t];
            }
    }
    __syncthreads();
    {
        const float* rb = red[1 - wv];
#pragma unroll
        for (int m2 = 0; m2 < 2; ++m2)
#pragma unroll
            for (int t = 0; t < 4; ++t) {
                int mt = wv * 2 + m2;
                int k = m2 * 4 + t;
                f32x4 o = *(const f32x4*)&rb[lane * 32 + ((k ^ (lane & 7)) << 2)];
                acc[mt][t] += o;
            }
    }
    __syncthreads();   // red dead; alias as per-wave transpose tiles

    // relu -> LDS transpose (32 rows/wave) -> coalesced dwordx4 stores
    bf16_t* tb = (bf16_t*)red + wv * 2304;
#pragma unroll
    for (int mt2 = 0; mt2 < 2; ++mt2)
#pragma unroll
        for (int t = 0; t < 4; ++t)
#pragma unroll
            for (int r = 0; r < 4; ++r) {
                float v = acc[wv * 2 + mt2][t][r];
                v = v > 0.0f ? v : 0.0f;
                tb[(mt2 * 16 + q * 4 + r) * TS + t * 16 + cl] = (bf16_t)v;
            }
#pragma unroll
    for (int i = 0; i < 4; ++i) {
        int rl = i * 8 + (lane >> 3);      // 0..31
        int c8 = (lane & 7) * 8;
        bf16x8 v8 = *(const bf16x8*)&tb[rl * TS + c8];
        int orow = base + wv * 32 + rl;
        if (orow < NC)
            *(bf16x8*)(y + (size_t)orow * 64 + c8) = v8;
    }
}

// ---------------------------------------------------------------------------
// Fused tconv + decoder, parent-centric (parent_idx[f] == f>>2 structurally).
// One wave = 16 parents = 64 fine rows. Per-wave LDS, no barriers. Low-VGPR
// (R2/R6 version, 69-70.7 us measured). 2 waves/block, 18.9 KB LDS ->
// 8 resident blocks/CU. Epilogue: fp32 LDS transpose -> coalesced float4.
// Grid must be a multiple of 8.
// ---------------------------------------------------------------------------
#define HS 72   // bf16 tile row stride (144 B) == 36-float rows
__global__ __launch_bounds__(128) void tconv_dec_k(
    const int*   __restrict__ offs,   // [MF]
    const float* __restrict__ b_t,
    const float* __restrict__ b_d1,
    const float* __restrict__ b_d2,
    const float* __restrict__ x_up,   // [MF, 32] fp32
    float*       __restrict__ out)    // [MF, 32] fp32
{
    __shared__ __align__(16) bf16_t h_lds[2][64 * HS];   // 9216 B / wave
    __shared__ __align__(16) int off_lds[2][64];
    int wv = threadIdx.x >> 6, lane = threadIdx.x & 63;
    int cl = lane & 15, q = lane >> 4;
    int per = gridDim.x >> 3;
    int blk = (blockIdx.x & 7) * per + (blockIdx.x >> 3);
    int p0 = (blk * 2 + wv) * 16;
    int fbase = p0 * 4;

    // stage the 64 children's offsets (per-wave)
    {
        int fi = fbase + lane;
        off_lds[wv][lane] = (fi < MF) ? offs[fi] : 0;
    }
    // per-m code: nibble at position k = (child j)+1 where offs[4m+j]==k
    int code[4];
#pragma unroll
    for (int r = 0; r < 4; ++r) {
        int4 o = *(const int4*)&off_lds[wv][(q * 4 + r) * 4];
        code[r] = (1 << (4 * o.x)) | (2 << (4 * o.y)) |
                  (3 << (4 * o.z)) | (4 << (4 * o.w));
    }

    // load X A-frags (parents p0+cl, rows of g_x1)
    bool pv = (p0 + cl) < NC;
    size_t xrow = (size_t)(pv ? p0 + cl : 0) * 64;
    bf16x8 ax[2];
#pragma unroll
    for (int c = 0; c < 2; ++c) {
        bf16x8 t8 = *(const bf16x8*)(g_x1 + xrow + c * 32 + q * 8);
        ax[c] = pv ? t8 : zero8();
    }

    const bf16_t* wt = g_w + O_T;
#pragma unroll
    for (int k = 0; k < 8; ++k) {
        f32x4 acc[4];
#pragma unroll
        for (int t = 0; t < 4; ++t) {
            float b = b_t[t * 16 + cl];
            acc[t] = (f32x4){b, b, b, b};
        }
#pragma unroll
        for (int c = 0; c < 2; ++c) {
            const bf16_t* wb = wt + ((size_t)(k * 2 + c) * 4) * 512 + lane * 8;
#pragma unroll
            for (int t = 0; t < 4; ++t) {
                bf16x8 b = *(const bf16x8*)(wb + t * 512);
                acc[t] = __builtin_amdgcn_mfma_f32_16x16x32_bf16(ax[c], b, acc[t], 0, 0, 0);
            }
        }
        // scatter selected child rows into h1 tile (per-wave)
#pragma unroll
        for (int r = 0; r < 4; ++r) {
            int nib = (code[r] >> (4 * k)) & 0xF;
            if (nib) {
                int fl = (((q * 4 + r) * 4) + (nib - 1)) & 63;
#pragma unroll
                for (int t = 0; t < 4; ++t) {
                    float v = acc[t][r];
                    v = v > 0.0f ? v : 0.0f;
                    h_lds[wv][fl * HS + t * 16 + cl] = (bf16_t)v;
                }
            }
        }
    }

    // ---- decoder stage 1: h2 = relu(h1) @ W_d1 + b_d1 ----
    bf16x8 a1[4][2];
#pragma unroll
    for (int mt = 0; mt < 4; ++mt)
#pragma unroll
        for (int c = 0; c < 2; ++c)
            a1[mt][c] = *(const bf16x8*)&h_lds[wv][(mt * 16 + cl) * HS + c * 32 + q * 8];

#pragma unroll
    for (int mt = 0; mt < 4; ++mt) {
        f32x4 acc2[4];
#pragma unroll
        for (int t = 0; t < 4; ++t) {
            float b = b_d1[t * 16 + cl];
            acc2[t] = (f32x4){b, b, b, b};
        }
#pragma unroll
        for (int c = 0; c < 2; ++c)
#pragma unroll
            for (int t = 0; t < 4; ++t) {
                bf16x8 b = *(const bf16x8*)(g_w + O_D1 + (size_t)(c * 4 + t) * 512 + lane * 8);
                acc2[t] = __builtin_amdgcn_mfma_f32_16x16x32_bf16(a1[mt][c], b, acc2[t], 0, 0, 0);
            }
#pragma unroll
        for (int t = 0; t < 4; ++t)
#pragma unroll
            for (int r = 0; r < 4; ++r) {
                float v = acc2[t][r];
                v = v > 0.0f ? v : 0.0f;
                h_lds[wv][(mt * 16 + q * 4 + r) * HS + t * 16 + cl] = (bf16_t)v;
            }
    }

    // ---- decoder stage 2: h3 = relu(h2) @ W_d2 + b_d2, fp32 into same rows --
    float* fW = (float*)h_lds[wv];
#pragma unroll
    for (int mt = 0; mt < 4; ++mt) {
        bf16x8 a2[2];
#pragma unroll
        for (int c = 0; c < 2; ++c)
            a2[c] = *(const bf16x8*)&h_lds[wv][(mt * 16 + cl) * HS + c * 32 + q * 8];
        f32x4 acc3[2];
#pragma unroll
        for (int t = 0; t < 2; ++t) {
            float b = b_d2[t * 16 + cl];
            acc3[t] = (f32x4){b, b, b, b};
        }
#pragma unroll
        for (int c = 0; c < 2; ++c)
#pragma unroll
            for (int t = 0; t < 2; ++t) {
                bf16x8 b = *(const bf16x8*)(g_w + O_D2 + (size_t)(c * 2 + t) * 512 + lane * 8);
                acc3[t] = __builtin_amdgcn_mfma_f32_16x16x32_bf16(a2[c], b, acc3[t], 0, 0, 0);
            }
#pragma unroll
        for (int t = 0; t < 2; ++t)
#pragma unroll
            for (int r = 0; r < 4; ++r)
                fW[(mt * 16 + q * 4 + r) * 36 + t * 16 + cl] = acc3[t][r];
    }

    // ---- coalesced epilogue: out = h3 + x_up (float4/lane) ----
#pragma unroll
    for (int i = 0; i < 8; ++i) {
        int rl = i * 8 + (lane >> 3);
        int c4 = (lane & 7) * 4;
        int fg = fbase + rl;
        if (fg < MF) {
            f32x4 xv = *(const f32x4*)(x_up + (size_t)fg * 32 + c4);
            f32x4 v = *(const f32x4*)&fW[rl * 36 + c4];
            v += xv;
            *(f32x4*)(out + (size_t)fg * 32 + c4) = v;
        }
    }
}

// ---------------------------------------------------------------------------
extern "C" void kernel_launch(void* const* d_in, const int* in_sizes, int n_in,
                              void* d_out, int out_size, void* d_ws, size_t ws_size,
                              hipStream_t stream) {
    const float* feats  = (const float*)d_in[0];
    const float* x_up   = (const float*)d_in[1];
    const int*   nbr    = (const int*)d_in[2];
    const int*   offs   = (const int*)d_in[4];
    const float* W_e1 = (const float*)d_in[5];
    const float* b_e1 = (const float*)d_in[6];
    const float* W_e2 = (const float*)d_in[7];
    const float* b_e2 = (const float*)d_in[8];
    const float* W_e3 = (const float*)d_in[9];
    const float* b_e3 = (const float*)d_in[10];
    const float* W_t  = (const float*)d_in[11];
    const float* b_t  = (const float*)d_in[12];
    const float* W_d1 = (const float*)d_in[13];
    const float* b_d1 = (const float*)d_in[14];
    const float* W_d2 = (const float*)d_in[15];
    const float* b_d2 = (const float*)d_in[16];
    float* out = (float*)d_out;

    // prep: 154 repack + 1563 feats + 391 nbr-transpose blocks
    prep_k<<<2108, 256, 0, stream>>>(W_e1, W_e2, W_e3, W_t, W_d1, W_d2, feats, nbr);

    // conv1 (CH=1): LDS-B, 32 rows/wave, 64 rows/block -> 1563 -> pad 1568
    convA_k<<<1568, 128, 0, stream>>>(b_e1);
    // conv2/3 (CH=2): K-split register-B, 64 rows/block -> 1563 -> pad 1568
    convB_k<<<1568, 128, 0, stream>>>(O_E2, b_e2, 1);
    convB_k<<<1568, 128, 0, stream>>>(O_E3, b_e3, 2);

    // tconv+decoder: 16 parents/wave, 2 waves/block -> ceil(6250/2)=3125 -> 3128
    tconv_dec_k<<<3128, 128, 0, stream>>>(offs, b_t, b_d1, b_d2, x_up, out);
}

// Round 9
// 285.134 us; speedup vs baseline: 1.2516x; 1.2516x over previous
//
#include <hip/hip_runtime.h>
#include <hip/hip_bf16.h>

// ---------------------------------------------------------------------------
// UpSampler: 3x sparse 3^3 conv (MFMA bf16, LDS-staged B) -> fused tconv+dec
// R9: R6 geometry verbatim (32 rows/wave, 2 waves/block, grid 1568, ~110
//     VGPR) with ONE change: the per-ko __syncthreads (which drains vmcnt(0)
//     and exposes ~400cyc of A-gather latency x27) is replaced by the
//     T3/T4 counted-vmcnt pattern: B staged via global_load_lds (linear
//     dest), issue order pinned [B | sched_barrier | A | idx], then
//     s_waitcnt vmcnt(N_younger_than_B) + raw s_barrier + sched_barrier(0).
//     A-gathers stay in flight across the barrier. Loop peeled at ko=24/25/26
//     so every vmcnt immediate is exact.
//     tconv_dec_k / prep_k: R6 verbatim.
// ---------------------------------------------------------------------------
#define NC 100000      // N_COARSE
#define MF 400000      // M_FINE
#define K3 27

typedef __bf16 bf16_t;
typedef bf16_t bf16x8 __attribute__((ext_vector_type(8)));
typedef float  f32x4  __attribute__((ext_vector_type(4)));

// Repacked-weight offsets (elements) inside g_w
#define O_E1 0                       // 27*1*4*512 = 55296
#define O_E2 55296                   // 27*2*4*512 = 110592
#define O_E3 165888                  // 110592
#define O_T  276480                  // 8*2*4*512 = 32768
#define O_D1 309248                  // 2*4*512 = 4096
#define O_D2 313344                  // 2*2*512 = 2048
#define W_TOTAL 315392

__device__ __align__(16) bf16_t g_w[W_TOTAL];
__device__ __align__(16) bf16_t g_x0[(size_t)NC * 32];  // bf16 feats
__device__ __align__(16) bf16_t g_x1[(size_t)NC * 64];
__device__ __align__(16) bf16_t g_x2[(size_t)NC * 64];
__device__ int g_nbrT[(size_t)K3 * NC];                 // transposed rulebook

static __device__ __forceinline__ bf16x8 zero8() {
    bf16x8 v;
#pragma unroll
    for (int i = 0; i < 8; ++i) v[i] = (bf16_t)0.0f;
    return v;
}

// ---------------------------------------------------------------------------
// Fused prep: (a) repack fp32 weights -> bf16 MFMA B-frags; (b) feats fp32 ->
// bf16; (c) transpose nbr [NC,27] -> g_nbrT [27,NC].
// Blocks [0,154): repack. [154,1717): feats. [1717,2108): nbr transpose.
// ---------------------------------------------------------------------------
__global__ __launch_bounds__(256) void prep_k(
    const float* __restrict__ W_e1, const float* __restrict__ W_e2,
    const float* __restrict__ W_e3, const float* __restrict__ W_t,
    const float* __restrict__ W_d1, const float* __restrict__ W_d2,
    const float* __restrict__ feats, const int* __restrict__ nbr)
{
    int b = blockIdx.x;
    if (b < 154) {
        int tid = b * 256 + threadIdx.x;
        int lane = tid & 63;
        int f = tid >> 6;            // 0..615
        const float* src; int doff, nt, nc, fb;
        if      (f < 108) { src = W_e1; doff = O_E1; nt = 4; nc = 1; fb = 0;   }
        else if (f < 324) { src = W_e2; doff = O_E2; nt = 4; nc = 2; fb = 108; }
        else if (f < 540) { src = W_e3; doff = O_E3; nt = 4; nc = 2; fb = 324; }
        else if (f < 604) { src = W_t;  doff = O_T;  nt = 4; nc = 2; fb = 540; }
        else if (f < 612) { src = W_d1; doff = O_D1; nt = 4; nc = 2; fb = 604; }
        else              { src = W_d2; doff = O_D2; nt = 2; nc = 2; fb = 612; }
        int lf = f - fb;
        int t  = lf % nt;
        int c  = (lf / nt) % nc;
        int ko = lf / (nt * nc);
        int Cin = nc * 32, Cout = nt * 16;
        int n  = t * 16 + (lane & 15);
        int kb = c * 32 + (lane >> 4) * 8;
        bf16x8 tmp;
#pragma unroll
        for (int j = 0; j < 8; ++j)
            tmp[j] = (bf16_t)src[((size_t)ko * Cin + (kb + j)) * Cout + n];
        *(bf16x8*)(g_w + doff + (size_t)lf * 512 + lane * 8) = tmp;
    } else if (b < 1717) {
        int i = (b - 154) * 256 + threadIdx.x;   // chunk of 8 floats
        if (i < NC * 32 / 8) {
            const f32x4* p = (const f32x4*)(feats + (size_t)i * 8);
            f32x4 lo = p[0], hi = p[1];
            bf16x8 v;
#pragma unroll
            for (int j = 0; j < 4; ++j) { v[j] = (bf16_t)lo[j]; v[j + 4] = (bf16_t)hi[j]; }
            *(bf16x8*)(g_x0 + (size_t)i * 8) = v;
        }
    } else {
        int r = (b - 1717) * 256 + threadIdx.x;
        if (r < NC) {
#pragma unroll
            for (int k = 0; k < K3; ++k)
                g_nbrT[(size_t)k * NC + r] = nbr[(size_t)r * K3 + k];
        }
    }
}

// ---------------------------------------------------------------------------
// Sparse 3^3 conv: 2 waves/block, 32 rows/wave. B[ko] double-buffered in LDS
// via global_load_lds (each wave stages its half). Counted-vmcnt barrier:
// per step, issue [B(ko+1) | sched_barrier | A(ko+1) | idx(ko+2)], compute
// MFMA(ko), then s_waitcnt vmcnt(CH*2+2) (= loads younger than B) + raw
// s_barrier. A-gathers survive the barrier; compiler waits them at consume.
// Peeled steps 24 (full, N=CH*2+2), 25 (no idx, N=CH*2), 26 (compute only).
// Grid must be a multiple of 8 (XCD swizzle).
// ---------------------------------------------------------------------------
#define TS 72   // transpose row stride (bf16): 144B, 16B-aligned

#define STAGE_B(KO, P) do {                                                    \
    _Pragma("unroll")                                                          \
    for (int i_ = 0; i_ < CH * 2; ++i_) {                                      \
        const bf16_t* gs_ = wsrc + (size_t)(KO) * CH * 2048                    \
                          + wv * (CH * 1024) + i_ * 512 + lane * 8;            \
        __builtin_amdgcn_global_load_lds(                                      \
            (const __attribute__((address_space(1))) void*)gs_,                \
            (__attribute__((address_space(3))) void*)                          \
                (&bB[P][wv * (CH * 1024) + i_ * 512 + lane * 8]),              \
            16, 0, 0);                                                         \
    }                                                                          \
} while (0)

#define GATHER_A(P) do {                                                       \
    _Pragma("unroll")                                                          \
    for (int c_ = 0; c_ < CH; ++c_)                                            \
        _Pragma("unroll")                                                      \
        for (int mt_ = 0; mt_ < 2; ++mt_) {                                    \
            int ii_ = idxbuf[P][mt_];                                          \
            bool va_ = (unsigned)ii_ < (unsigned)NC;                           \
            int ss_ = va_ ? ii_ : 0;                                           \
            bf16x8 a_ = *(const bf16x8*)(xb + (size_t)ss_ * CIN + c_ * 32 + q * 8); \
            if (!va_) a_ = zero8();                                            \
            abuf[P][c_][mt_] = a_;                                             \
        }                                                                      \
} while (0)

#define LOAD_IDX(KO, P) do {                                                   \
    _Pragma("unroll")                                                          \
    for (int mt_ = 0; mt_ < 2; ++mt_) {                                        \
        int r_ = base + mt_ * 16 + cl;                                         \
        idxbuf[P][mt_] = (r_ < NC) ? g_nbrT[(size_t)(KO) * NC + r_] : NC;      \
    }                                                                          \
} while (0)

#define MFMA_KO(P) do {                                                        \
    _Pragma("unroll")                                                          \
    for (int c_ = 0; c_ < CH; ++c_) {                                          \
        bf16x8 bfr_[4];                                                        \
        _Pragma("unroll")                                                      \
        for (int t_ = 0; t_ < 4; ++t_)                                         \
            bfr_[t_] = *(const bf16x8*)&bB[P][(c_ * 4 + t_) * 512 + lane * 8]; \
        _Pragma("unroll")                                                      \
        for (int mt_ = 0; mt_ < 2; ++mt_)                                      \
            _Pragma("unroll")                                                  \
            for (int t_ = 0; t_ < 4; ++t_)                                     \
                acc[mt_][t_] = __builtin_amdgcn_mfma_f32_16x16x32_bf16(        \
                    abuf[P][c_][mt_], bfr_[t_], acc[mt_][t_], 0, 0, 0);        \
    }                                                                          \
} while (0)

#define CSTEP_FULL(KO, P) do {                                                 \
    STAGE_B((KO) + 1, (P) ^ 1);                                                \
    __builtin_amdgcn_sched_barrier(0);   /* pin: B issued before A/idx */      \
    GATHER_A((P) ^ 1);                                                         \
    LOAD_IDX((KO) + 2, P);                                                     \
    MFMA_KO(P);                                                                \
    asm volatile("s_waitcnt vmcnt(%0)\n\ts_barrier"                            \
                 :: "i"(CH * 2 + 2) : "memory");                               \
    __builtin_amdgcn_sched_barrier(0);   /* rule #18 fence */                  \
} while (0)

#define CSTEP_PEN(KO, P) do {            /* penultimate: no idx prefetch */    \
    STAGE_B((KO) + 1, (P) ^ 1);                                                \
    __builtin_amdgcn_sched_barrier(0);                                         \
    GATHER_A((P) ^ 1);                                                         \
    MFMA_KO(P);                                                                \
    asm volatile("s_waitcnt vmcnt(%0)\n\ts_barrier"                            \
                 :: "i"(CH * 2) : "memory");                                   \
    __builtin_amdgcn_sched_barrier(0);                                         \
} while (0)

template <int CH>
__global__ __launch_bounds__(128, 2) void conv_k(
    int w_off,
    const float* __restrict__ bias,  // [64] fp32
    int src_sel, int dst_sel)        // 0 = g_x0, 1 = g_x1, 2 = g_x2
{
    constexpr int CIN = CH * 32;
    const bf16_t* xb = (src_sel == 0) ? g_x0 : (src_sel == 1 ? g_x1 : g_x2);
    bf16_t* y = (dst_sel == 1) ? g_x1 : g_x2;
    const bf16_t* wsrc = g_w + w_off;

    __shared__ __align__(16) bf16_t bB[2][4096];   // 16 KB (fixed: transpose
                                                   // reuse needs 4608/wave)
    int tid = threadIdx.x;
    int wv = tid >> 6, lane = tid & 63;
    int cl = lane & 15, q = lane >> 4;

    int per = gridDim.x >> 3;
    int blk = (blockIdx.x & 7) * per + (blockIdx.x >> 3);
    int base = blk * 64 + wv * 32;   // 32 rows per wave

    int idxbuf[2][2];
    bf16x8 abuf[2][CH][2];

    // prologue: idx[0] -> A[0]; idx[1]; B[0] staged async; full drain once.
    LOAD_IDX(0, 0);
    GATHER_A(0);
    LOAD_IDX(1, 1);
    STAGE_B(0, 0);

    f32x4 acc[2][4];
#pragma unroll
    for (int t = 0; t < 4; ++t) {
        float b = bias[t * 16 + cl];
#pragma unroll
        for (int mt = 0; mt < 2; ++mt) acc[mt][t] = (f32x4){b, b, b, b};
    }
    __syncthreads();   // one-time full drain: B[0] + prologue loads

    for (int ko = 0; ko < 24; ko += 2) {
        CSTEP_FULL(ko, 0);
        CSTEP_FULL(ko + 1, 1);
    }
    CSTEP_FULL(24, 0);   // stages B25/A25, idx26
    CSTEP_PEN(25, 1);    // stages B26/A26
    MFMA_KO(0);          // ko = 26
    __syncthreads();     // before transpose reuse of bB

    // relu -> per-wave LDS transpose (reuse bB) -> coalesced dwordx4 stores
    bf16_t* tb = ((bf16_t*)bB) + wv * 2304;   // 32 rows * 72 per wave
#pragma unroll
    for (int mt2 = 0; mt2 < 2; ++mt2)
#pragma unroll
        for (int t = 0; t < 4; ++t)
#pragma unroll
            for (int r = 0; r < 4; ++r) {
                float v = acc[mt2][t][r];
                v = v > 0.0f ? v : 0.0f;
                tb[(mt2 * 16 + q * 4 + r) * TS + t * 16 + cl] = (bf16_t)v;
            }
#pragma unroll
    for (int i = 0; i < 4; ++i) {
        int rl = i * 8 + (lane >> 3);      // 0..31
        int c8 = (lane & 7) * 8;
        bf16x8 v8 = *(const bf16x8*)&tb[rl * TS + c8];
        int orow = base + rl;
        if (orow < NC)
            *(bf16x8*)(y + (size_t)orow * 64 + c8) = v8;
    }
}

// ---------------------------------------------------------------------------
// Fused tconv + decoder, parent-centric (parent_idx[f] == f>>2 structurally).
// One wave = 16 parents = 64 fine rows. Per-wave LDS, no barriers. Low-VGPR
// (R2/R6 version, 69-70.7 us measured). 2 waves/block, 18.9 KB LDS ->
// 8 resident blocks/CU. Epilogue: fp32 LDS transpose -> coalesced float4.
// Grid must be a multiple of 8.
// ---------------------------------------------------------------------------
#define HS 72   // bf16 tile row stride (144 B) == 36-float rows
__global__ __launch_bounds__(128) void tconv_dec_k(
    const int*   __restrict__ offs,   // [MF]
    const float* __restrict__ b_t,
    const float* __restrict__ b_d1,
    const float* __restrict__ b_d2,
    const float* __restrict__ x_up,   // [MF, 32] fp32
    float*       __restrict__ out)    // [MF, 32] fp32
{
    __shared__ __align__(16) bf16_t h_lds[2][64 * HS];   // 9216 B / wave
    __shared__ __align__(16) int off_lds[2][64];
    int wv = threadIdx.x >> 6, lane = threadIdx.x & 63;
    int cl = lane & 15, q = lane >> 4;
    int per = gridDim.x >> 3;
    int blk = (blockIdx.x & 7) * per + (blockIdx.x >> 3);
    int p0 = (blk * 2 + wv) * 16;
    int fbase = p0 * 4;

    // stage the 64 children's offsets (per-wave)
    {
        int fi = fbase + lane;
        off_lds[wv][lane] = (fi < MF) ? offs[fi] : 0;
    }
    // per-m code: nibble at position k = (child j)+1 where offs[4m+j]==k
    int code[4];
#pragma unroll
    for (int r = 0; r < 4; ++r) {
        int4 o = *(const int4*)&off_lds[wv][(q * 4 + r) * 4];
        code[r] = (1 << (4 * o.x)) | (2 << (4 * o.y)) |
                  (3 << (4 * o.z)) | (4 << (4 * o.w));
    }

    // load X A-frags (parents p0+cl, rows of g_x1)
    bool pv = (p0 + cl) < NC;
    size_t xrow = (size_t)(pv ? p0 + cl : 0) * 64;
    bf16x8 ax[2];
#pragma unroll
    for (int c = 0; c < 2; ++c) {
        bf16x8 t8 = *(const bf16x8*)(g_x1 + xrow + c * 32 + q * 8);
        ax[c] = pv ? t8 : zero8();
    }

    const bf16_t* wt = g_w + O_T;
#pragma unroll
    for (int k = 0; k < 8; ++k) {
        f32x4 acc[4];
#pragma unroll
        for (int t = 0; t < 4; ++t) {
            float b = b_t[t * 16 + cl];
            acc[t] = (f32x4){b, b, b, b};
        }
#pragma unroll
        for (int c = 0; c < 2; ++c) {
            const bf16_t* wb = wt + ((size_t)(k * 2 + c) * 4) * 512 + lane * 8;
#pragma unroll
            for (int t = 0; t < 4; ++t) {
                bf16x8 b = *(const bf16x8*)(wb + t * 512);
                acc[t] = __builtin_amdgcn_mfma_f32_16x16x32_bf16(ax[c], b, acc[t], 0, 0, 0);
            }
        }
        // scatter selected child rows into h1 tile (per-wave)
#pragma unroll
        for (int r = 0; r < 4; ++r) {
            int nib = (code[r] >> (4 * k)) & 0xF;
            if (nib) {
                int fl = (((q * 4 + r) * 4) + (nib - 1)) & 63;
#pragma unroll
                for (int t = 0; t < 4; ++t) {
                    float v = acc[t][r];
                    v = v > 0.0f ? v : 0.0f;
                    h_lds[wv][fl * HS + t * 16 + cl] = (bf16_t)v;
                }
            }
        }
    }

    // ---- decoder stage 1: h2 = relu(h1) @ W_d1 + b_d1 ----
    bf16x8 a1[4][2];
#pragma unroll
    for (int mt = 0; mt < 4; ++mt)
#pragma unroll
        for (int c = 0; c < 2; ++c)
            a1[mt][c] = *(const bf16x8*)&h_lds[wv][(mt * 16 + cl) * HS + c * 32 + q * 8];

#pragma unroll
    for (int mt = 0; mt < 4; ++mt) {
        f32x4 acc2[4];
#pragma unroll
        for (int t = 0; t < 4; ++t) {
            float b = b_d1[t * 16 + cl];
            acc2[t] = (f32x4){b, b, b, b};
        }
#pragma unroll
        for (int c = 0; c < 2; ++c)
#pragma unroll
            for (int t = 0; t < 4; ++t) {
                bf16x8 b = *(const bf16x8*)(g_w + O_D1 + (size_t)(c * 4 + t) * 512 + lane * 8);
                acc2[t] = __builtin_amdgcn_mfma_f32_16x16x32_bf16(a1[mt][c], b, acc2[t], 0, 0, 0);
            }
#pragma unroll
        for (int t = 0; t < 4; ++t)
#pragma unroll
            for (int r = 0; r < 4; ++r) {
                float v = acc2[t][r];
                v = v > 0.0f ? v : 0.0f;
                h_lds[wv][(mt * 16 + q * 4 + r) * HS + t * 16 + cl] = (bf16_t)v;
            }
    }

    // ---- decoder stage 2: h3 = relu(h2) @ W_d2 + b_d2, fp32 into same rows --
    float* fW = (float*)h_lds[wv];
#pragma unroll
    for (int mt = 0; mt < 4; ++mt) {
        bf16x8 a2[2];
#pragma unroll
        for (int c = 0; c < 2; ++c)
            a2[c] = *(const bf16x8*)&h_lds[wv][(mt * 16 + cl) * HS + c * 32 + q * 8];
        f32x4 acc3[2];
#pragma unroll
        for (int t = 0; t < 2; ++t) {
            float b = b_d2[t * 16 + cl];
            acc3[t] = (f32x4){b, b, b, b};
        }
#pragma unroll
        for (int c = 0; c < 2; ++c)
#pragma unroll
            for (int t = 0; t < 2; ++t) {
                bf16x8 b = *(const bf16x8*)(g_w + O_D2 + (size_t)(c * 2 + t) * 512 + lane * 8);
                acc3[t] = __builtin_amdgcn_mfma_f32_16x16x32_bf16(a2[c], b, acc3[t], 0, 0, 0);
            }
#pragma unroll
        for (int t = 0; t < 2; ++t)
#pragma unroll
            for (int r = 0; r < 4; ++r)
                fW[(mt * 16 + q * 4 + r) * 36 + t * 16 + cl] = acc3[t][r];
    }

    // ---- coalesced epilogue: out = h3 + x_up (float4/lane) ----
#pragma unroll
    for (int i = 0; i < 8; ++i) {
        int rl = i * 8 + (lane >> 3);
        int c4 = (lane & 7) * 4;
        int fg = fbase + rl;
        if (fg < MF) {
            f32x4 xv = *(const f32x4*)(x_up + (size_t)fg * 32 + c4);
            f32x4 v = *(const f32x4*)&fW[rl * 36 + c4];
            v += xv;
            *(f32x4*)(out + (size_t)fg * 32 + c4) = v;
        }
    }
}

// ---------------------------------------------------------------------------
extern "C" void kernel_launch(void* const* d_in, const int* in_sizes, int n_in,
                              void* d_out, int out_size, void* d_ws, size_t ws_size,
                              hipStream_t stream) {
    const float* feats  = (const float*)d_in[0];
    const float* x_up   = (const float*)d_in[1];
    const int*   nbr    = (const int*)d_in[2];
    const int*   offs   = (const int*)d_in[4];
    const float* W_e1 = (const float*)d_in[5];
    const float* b_e1 = (const float*)d_in[6];
    const float* W_e2 = (const float*)d_in[7];
    const float* b_e2 = (const float*)d_in[8];
    const float* W_e3 = (const float*)d_in[9];
    const float* b_e3 = (const float*)d_in[10];
    const float* W_t  = (const float*)d_in[11];
    const float* b_t  = (const float*)d_in[12];
    const float* W_d1 = (const float*)d_in[13];
    const float* b_d1 = (const float*)d_in[14];
    const float* W_d2 = (const float*)d_in[15];
    const float* b_d2 = (const float*)d_in[16];
    float* out = (float*)d_out;

    // prep: 154 repack + 1563 feats + 391 nbr-transpose blocks
    prep_k<<<2108, 256, 0, stream>>>(W_e1, W_e2, W_e3, W_t, W_d1, W_d2, feats, nbr);

    // conv: 2 waves/block, 32 rows/wave (64/block) -> 1563 tiles -> pad 1568
    conv_k<1><<<1568, 128, 0, stream>>>(O_E1, b_e1, 0, 1);
    conv_k<2><<<1568, 128, 0, stream>>>(O_E2, b_e2, 1, 2);
    conv_k<2><<<1568, 128, 0, stream>>>(O_E3, b_e3, 2, 1);

    // tconv+decoder: 16 parents/wave, 2 waves/block -> ceil(6250/2)=3125 -> 3128
    tconv_dec_k<<<3128, 128, 0, stream>>>(offs, b_t, b_d1, b_d2, x_up, out);
}